// Round 6
// baseline (219.964 us; speedup 1.0000x reference)
//
#include <hip/hip_runtime.h>

// LoRA linear, fp32 in/out: out = x @ (W + 2*B@A)^T + b
//   prep:   Weff = bf16(W + 2*B@A) only (2 MiB, 512 blocks, ~3us). No xbf pass —
//           gemm reads x fp32 directly (R4), saving ~15us of fixed cost.
//   gemm256: 256x128x32 2-phase bf16 MFMA GEMM, 2 blocks/CU (48 KiB LDS).
//           R5: A reg-staging pipeline deepened to DISTANCE-2 tiles (R4 had
//           distance-1 -> exposed HBM latency every tile, 85us). Two parity-bound
//           reg sets sEV/sOD (static indexing via explicit 2-tile body, rule #20):
//           set loaded at tile j p1 = A(j+3), published at tile j+2 p0. The
//           vmcnt(5) checkpoint at each p1 retires {prior-parity A-set x4, B(j+1)}
//           so the publish's compiler wait is already satisfied (no stall).
//           Swizzle (R4-verified, conflicts=0): chunk c of row r at pos c^((r>>1)&3).
//           (R6 = R5 resubmit: R5 bench was a container/infra failure; schedule
//           re-audited — barriers uniform, vmcnt ledger exact, bounds safe.)
//   Fallback (ws too small): old 128x128 kernel, A staged via fp32 loads + HW cvt.

typedef __bf16 bf16x8 __attribute__((ext_vector_type(8)));
typedef float f32x4 __attribute__((ext_vector_type(4)));
typedef unsigned short ushort8 __attribute__((ext_vector_type(8)));

__device__ __forceinline__ unsigned short f2bf(float f) {
    __bf16 h = (__bf16)f;                       // HW RNE convert
    union { __bf16 b; unsigned short u; } v; v.b = h; return v.u;
}
__device__ __forceinline__ ushort8 cvt8(f32x4 a, f32x4 b) {
    ushort8 o;
#pragma unroll
    for (int i = 0; i < 4; ++i) { o[i] = f2bf(a[i]); o[i + 4] = f2bf(b[i]); }
    return o;
}
__device__ __forceinline__ void gld16(const unsigned short* g, unsigned short* l) {
    __builtin_amdgcn_global_load_lds(
        (const __attribute__((address_space(1))) unsigned int*)g,
        (__attribute__((address_space(3))) unsigned int*)l, 16, 0, 0);
}

#define FENCE() asm volatile("" ::: "memory")
#define BARRIER() do { FENCE(); __builtin_amdgcn_s_barrier(); FENCE(); } while (0)

// ---------------- prep: Weff fold only (512 blocks) ----------------
__global__ __launch_bounds__(256) void prep(
    const float* __restrict__ W, const float* __restrict__ A,
    const float* __restrict__ B, unsigned short* __restrict__ Weff)
{
    const int idx = blockIdx.x * 256 + threadIdx.x;
    const int o  = idx >> 7;
    const int kc = (idx & 127) << 3;
    float br[16];
#pragma unroll
    for (int r = 0; r < 16; ++r) br[r] = 2.0f * B[o * 16 + r];
    float acc[8];
    const float* wrow = W + (size_t)o * 1024 + kc;
#pragma unroll
    for (int j = 0; j < 8; ++j) acc[j] = wrow[j];
#pragma unroll
    for (int r = 0; r < 16; ++r) {
        const float* arow = A + r * 1024 + kc;
#pragma unroll
        for (int j = 0; j < 8; ++j) acc[j] += br[r] * arow[j];
    }
    ushort8 o8;
#pragma unroll
    for (int j = 0; j < 8; ++j) o8[j] = f2bf(acc[j]);
    *(ushort8*)(Weff + (size_t)o * 1024 + kc) = o8;
}

// ---------------- gemm256: 256x128x32, 2 phases/tile, 2 blocks/CU ----------------
// Geometry: BM=256, BN=128, BK=32, 512 thr = 8 waves (2M x 4N). Per-wave out
//   128x32: m-frags rows (2*mt+wr)*16 (mt<4 in A0-half, mt>=4 in A1), n-frags
//   cols (wc+4*nt)*16 (nt=0..1, single B region).
// LDS 48 KiB: 2 bufs x {A0:0, A1:4096, B:8192} ushorts ([128 rows][32] bf16).
// Swizzle: 16B-chunk c of row r at position c ^ ((r>>1)&3). Reader phase
//   (16 lanes, quad fixed): bank-group (4r+p)%8 covers all 8 groups 2x -> free.
//   A write-side 16-lane phase = 4 full rows -> 2-way, free. (R4: conflicts=0.)
// Pipeline (steady state, tile j):
//   p0: publish set[par(j)] = A(j+1) (cvt8 + swizzled ds_write_b128) -> NEXT buf
//       (regs loaded at j-2 p1, RETIRED by j-1 p1's vmcnt(5) -> no stall);
//       ds_read fa[0..3], fb[0..1] from CUR buf.
//   p1: ds_read fa[4..7]; load set[par(j)] = A(j+3) (4x dwordx4); gld16 B(j+2)
//       -> CUR buf B (last B read was this p0, drained by p0's lgkmcnt+barrier);
//       vmcnt(5): queue = [setOther A(j+2)x4, B(j+1), setThis A(j+3)x4, B(j+2)]
//       (10) -> retires setOther + B(j+1): B ready for j+1 p0, regs ready for
//       j+1 p0's publish. Peel: j=29 -> vmcnt(1); j=30 -> vmcnt(0); j=31 none;
//       A loads stop at j=28 (A(31)), B gld16 at j=29 (B(31)), publish at j=30.
#define PHASE_MFMA(LO)                                              \
    do { BARRIER();                                                 \
         asm volatile("s_waitcnt lgkmcnt(0)" ::: "memory");         \
         __builtin_amdgcn_sched_barrier(0); /* rule 18 */           \
         __builtin_amdgcn_s_setprio(1);                             \
         _Pragma("unroll")                                          \
         for (int m2 = 0; m2 < 4; ++m2)                             \
             _Pragma("unroll")                                      \
             for (int n2 = 0; n2 < 2; ++n2)                         \
                 acc[(LO) + m2][n2] = __builtin_amdgcn_mfma_f32_16x16x32_bf16( \
                     fa[(LO) + m2], fb[n2], acc[(LO) + m2][n2], 0, 0, 0);      \
         __builtin_amdgcn_s_setprio(0);                             \
         BARRIER(); } while (0)

#define LOADA(S, KT)                                                           \
    do { S[0] = *(const f32x4*)(gA0 + (KT)); S[1] = *(const f32x4*)(gA0 + (KT) + 4); \
         S[2] = *(const f32x4*)(gA1 + (KT)); S[3] = *(const f32x4*)(gA1 + (KT) + 4); \
         FENCE(); } while (0)

#define PUBA(S, BUF)                                                           \
    do { *(ushort8*)(lds + (BUF) + wd)        = cvt8(S[0], S[1]);              \
         *(ushort8*)(lds + (BUF) + 4096 + wd) = cvt8(S[2], S[3]);              \
         FENCE(); } while (0)

__global__ __launch_bounds__(512, 4) void gemm256(
    const float* __restrict__ Xf,              // fp32 x [M][1024]
    const unsigned short* __restrict__ Wt,     // bf16 Weff [1024][1024]
    const float* __restrict__ bias,            // fp32 [1024]
    float* __restrict__ out)                   // fp32 [M][1024]
{
    extern __shared__ __align__(16) unsigned short lds[];   // 49152 B

    const int t    = threadIdx.x;
    const int lane = t & 63;
    const int w    = t >> 6;
    const int wr   = w >> 2;        // 0..1 (M)
    const int wc   = w & 3;         // 0..3 (N)
    const int r16  = lane & 15;
    const int quad = lane >> 4;

    // XCD-chunked block swizzle (nwg=512 % 8 == 0 -> bijective).
    const int nwg = gridDim.x;
    int swz = blockIdx.x;
    if ((nwg & 7) == 0) swz = (swz & 7) * (nwg >> 3) + (swz >> 3);
    const int bm = (swz >> 3) * 256;           // 64 m-panels
    const int bn = (swz & 7) * 128;            // 8 n-panels share one x panel (L2)

    // ---- staging constants: thread t owns chunk (row r, chunk c) ----
    const int r  = t >> 2;                     // half-local row 0..127
    const int c  = t & 3;
    const int xr = c ^ ((r >> 1) & 3);         // swizzle term
    const float* gA0 = Xf + (size_t)(bm + r) * 1024 + c * 8;   // 8 fp32 = 1 chunk
    const float* gA1 = gA0 + 131072;           // +128 rows
    const unsigned short* pB = Wt + (size_t)(bn + r) * 1024 + xr * 8;  // pre-swz src
    const int wd = r * 32 + xr * 8;            // swizzled A ds_write dest (ushorts)
    const int lc = t * 8;                      // linear B dest (ushorts)

    // ---- reader constants ----
    const int sw = (quad ^ ((r16 >> 1) & 3)) * 8;
    const int aB = wr * 512 + r16 * 32 + sw;
    const int bB = wc * 512 + r16 * 32 + sw;

    f32x4 acc[8][2];
#pragma unroll
    for (int i = 0; i < 8; ++i)
#pragma unroll
        for (int jj = 0; jj < 2; ++jj)
            acc[i][jj] = (f32x4){0.f, 0.f, 0.f, 0.f};

    f32x4 sEV[4], sOD[4];   // parity-bound A reg sets (static indexing, rule #20)

    // ---- prologue ----
    // Issue order (queue bookkeeping): A(0)x4, B(0), A(1)x4, B(1), A(2)x4.
    LOADA(sEV, 0);                                       // A(0)
    gld16(pB, lds + 8192 + lc);           FENCE();       // B(0) -> buf0
    PUBA(sEV, 0);                                        // A(0) -> buf0 (waits A(0))
    LOADA(sEV, 32);                                      // A(1) (publish @ tile0 p0)
    gld16(pB + 32, lds + 12288 + 8192 + lc); FENCE();    // B(1) -> buf1
    LOADA(sOD, 64);                                      // A(2) (publish @ tile1 p0)
    asm volatile("s_waitcnt vmcnt(9)" ::: "memory");     // retire B(0)
    asm volatile("s_waitcnt lgkmcnt(0)" ::: "memory");   // A(0) ds_writes drained
    BARRIER();

    for (int i = 0; i < 16; ++i) {
        // ================= even tile j=2i: cur=buf0, nxt=buf1 =================
        {
            bf16x8 fa[8], fb[2];
            // p0: publish A(j+1) -> buf1 (j<=30 always for even tiles)
            PUBA(sEV, 12288);
#pragma unroll
            for (int mt = 0; mt < 4; ++mt)
                fa[mt] = *(const bf16x8*)(lds + mt * 1024 + aB);
#pragma unroll
            for (int nt = 0; nt < 2; ++nt)
                fb[nt] = *(const bf16x8*)(lds + 8192 + nt * 2048 + bB);
            PHASE_MFMA(0);
            // p1
#pragma unroll
            for (int mt = 4; mt < 8; ++mt)
                fa[mt] = *(const bf16x8*)(lds + 4096 + (mt - 4) * 1024 + aB);
            if (i <= 14) {
                LOADA(sEV, (2 * i + 3) * 32);                       // A(j+3)
                gld16(pB + (2 * i + 2) * 32, lds + 8192 + lc);      // B(j+2) -> buf0
                FENCE();
                asm volatile("s_waitcnt vmcnt(5)" ::: "memory");
            } else {
                asm volatile("s_waitcnt vmcnt(0)" ::: "memory");    // j=30: B(31)
            }
            PHASE_MFMA(4);
        }
        // ================= odd tile j=2i+1: cur=buf1, nxt=buf0 =================
        {
            bf16x8 fa[8], fb[2];
            // p0: publish A(j+1) -> buf0 (skip at j=31)
            if (i <= 14) PUBA(sOD, 0);
#pragma unroll
            for (int mt = 0; mt < 4; ++mt)
                fa[mt] = *(const bf16x8*)(lds + 12288 + mt * 1024 + aB);
#pragma unroll
            for (int nt = 0; nt < 2; ++nt)
                fb[nt] = *(const bf16x8*)(lds + 12288 + 8192 + nt * 2048 + bB);
            PHASE_MFMA(0);
            // p1
#pragma unroll
            for (int mt = 4; mt < 8; ++mt)
                fa[mt] = *(const bf16x8*)(lds + 12288 + 4096 + (mt - 4) * 1024 + aB);
            if (i <= 13) LOADA(sOD, (2 * i + 4) * 32);                       // A(j+3)
            if (i <= 14) { gld16(pB + (2 * i + 3) * 32, lds + 12288 + 8192 + lc);  // B(j+2)
                           FENCE(); }
            if (i <= 13)      asm volatile("s_waitcnt vmcnt(5)" ::: "memory");
            else if (i == 14) asm volatile("s_waitcnt vmcnt(1)" ::: "memory"); // j=29
            /* i==15 (j=31): nothing outstanding */
            PHASE_MFMA(4);
        }
    }

    // ---- epilogue: frag (mt,nt) -> rows bm+(2mt+wr)*16+quad*4, cols bn+(wc+4nt)*16+r16 ----
    const int orow0 = bm + wr * 16 + quad * 4;
    const int ocol0 = bn + wc * 16 + r16;
#pragma unroll
    for (int nt = 0; nt < 2; ++nt) {
        const float bv = bias[ocol0 + nt * 64];
#pragma unroll
        for (int mt = 0; mt < 8; ++mt) {
            float* orow = out + (size_t)(orow0 + mt * 32) * 1024 + (ocol0 + nt * 64);
#pragma unroll
            for (int i = 0; i < 4; ++i)
                orow[(size_t)i * 1024] = acc[mt][nt][i] + bv;
        }
    }
}

// ---------------- fallback gemm (ws too small): old 128x128, fp32 A ----------------
template <bool XF32>
__global__ __launch_bounds__(256) void gemm_bt(
    const void* __restrict__ X_, const unsigned short* __restrict__ Wt,
    const float* __restrict__ bias, float* __restrict__ out)
{
    __shared__ __align__(16) unsigned short lA[128 * 32];
    __shared__ __align__(16) unsigned short lB[128 * 32];

    const int t    = threadIdx.x;
    const int lane = t & 63;
    const int w    = t >> 6;
    const int bm   = blockIdx.x * 128;
    const int bn   = blockIdx.y * 128;
    const int wm   = (w & 1) * 64;
    const int wn   = (w >> 1) * 64;
    const int r16  = lane & 15;
    const int quad = lane >> 4;

    const int srow = t >> 2;
    const int gc   = (t & 3) ^ ((srow >> 1) & 3);
    unsigned short* lsA = lA + t * 8;
    unsigned short* lsB = lB + t * 8;
    const size_t ga0 = (size_t)(bm + srow) * 1024 + gc * 8;
    const size_t ga1 = (size_t)(bm + srow + 64) * 1024 + gc * 8;
    const unsigned short* gB0 = Wt + (size_t)(bn + srow) * 1024 + gc * 8;

    const int p    = (quad ^ ((r16 >> 1) & 3)) * 8;
    const int aoff = (wm + r16) * 32 + p;
    const int boff = (wn + r16) * 32 + p;

    const unsigned short* Xb = (const unsigned short*)X_;
    const float*          Xf = (const float*)X_;

    f32x4 acc[4][4];
#pragma unroll
    for (int i = 0; i < 4; ++i)
#pragma unroll
        for (int j = 0; j < 4; ++j) {
            f32x4 z = {0.f, 0.f, 0.f, 0.f};
            acc[i][j] = z;
        }

    for (int kt = 0; kt < 1024; kt += 32) {
        if (XF32) {
            f32x4 a0 = *(const f32x4*)(Xf + ga0 + kt);
            f32x4 a1 = *(const f32x4*)(Xf + ga0 + kt + 4);
            f32x4 a2 = *(const f32x4*)(Xf + ga1 + kt);
            f32x4 a3 = *(const f32x4*)(Xf + ga1 + kt + 4);
            *(ushort8*)lsA          = cvt8(a0, a1);
            *(ushort8*)(lsA + 2048) = cvt8(a2, a3);
        } else {
            gld16(Xb + ga0 + kt, lsA);
            gld16(Xb + ga1 + kt, lsA + 2048);
        }
        gld16(gB0 + kt,             lsB);
        gld16(gB0 + kt + 64 * 1024, lsB + 2048);
        __syncthreads();

        bf16x8 fa[4], fb[4];
#pragma unroll
        for (int mt = 0; mt < 4; ++mt) fa[mt] = *(const bf16x8*)(lA + aoff + mt * 16 * 32);
#pragma unroll
        for (int nt = 0; nt < 4; ++nt) fb[nt] = *(const bf16x8*)(lB + boff + nt * 16 * 32);

#pragma unroll
        for (int mt = 0; mt < 4; ++mt)
#pragma unroll
            for (int nt = 0; nt < 4; ++nt)
                acc[mt][nt] = __builtin_amdgcn_mfma_f32_16x16x32_bf16(
                    fa[mt], fb[nt], acc[mt][nt], 0, 0, 0);

        __syncthreads();
    }

    const int orow0 = bm + wm + quad * 4;
    const int ocol0 = bn + wn + r16;
#pragma unroll
    for (int nt = 0; nt < 4; ++nt) {
        const float bv = bias[ocol0 + nt * 16];
#pragma unroll
        for (int mt = 0; mt < 4; ++mt)
#pragma unroll
            for (int i = 0; i < 4; ++i)
                out[(size_t)(orow0 + mt * 16 + i) * 1024 + (ocol0 + nt * 16)] =
                    acc[mt][nt][i] + bv;
    }
}

extern "C" void kernel_launch(void* const* d_in, const int* in_sizes, int n_in,
                              void* d_out, int out_size, void* d_ws, size_t ws_size,
                              hipStream_t stream) {
    const float* x  = (const float*)d_in[0];   // [M][1024]
    const float* W  = (const float*)d_in[1];   // [1024][1024]
    const float* b  = (const float*)d_in[2];   // [1024]
    const float* A  = (const float*)d_in[3];   // [16][1024]
    const float* Bm = (const float*)d_in[4];   // [1024][16]
    float* out = (float*)d_out;

    const int M = in_sizes[0] / 1024;          // 16384

    const bool fast = (ws_size >= (2u << 20) + 4096) && (M % 256 == 0);
    unsigned short* Weff = (unsigned short*)d_ws;
    hipLaunchKernelGGL(prep, dim3(512), dim3(256), 0, stream, W, A, Bm, Weff);
    if (fast) {
        hipLaunchKernelGGL(gemm256, dim3((M / 256) * 8), dim3(512), 49152, stream,
                           x, Weff, b, out);
    } else {
        hipLaunchKernelGGL((gemm_bt<true>), dim3(M / 128, 8), dim3(256), 0, stream,
                           (const void*)x, Weff, b, out);
    }
}

// Round 7
// 153.353 us; speedup vs baseline: 1.4344x; 1.4344x over previous
//
#include <hip/hip_runtime.h>

// LoRA linear, fp32 in/out: out = x @ (W + 2*B@A)^T + b
//   prep:   [0..511] Weff = bf16(W + 2*B@A) (2 MiB); [512..] xbf = bf16(x) (32 MiB)
//   gemm256: 256x128x32 2-phase bf16 MFMA GEMM, 2 blocks/CU (48 KiB LDS).
//           R7 = R3's verified schedule (gld16 both operands, counted vmcnt(2))
//           + R4's verified swizzle h(r)=(r>>1)&3 (conflicts=0). The fp32-direct
//           A path (R4/R6) is dead: dist-1 exposes HBM latency (85us), dist-2
//           spills (WRITE 146MB, 128us). xbf prep costs ~16us BW, gemm stays clean.
//   Fallback (ws too small): old 128x128 kernel, A staged via fp32 loads + HW cvt.

typedef __bf16 bf16x8 __attribute__((ext_vector_type(8)));
typedef float f32x4 __attribute__((ext_vector_type(4)));
typedef unsigned short ushort8 __attribute__((ext_vector_type(8)));

__device__ __forceinline__ unsigned short f2bf(float f) {
    __bf16 h = (__bf16)f;                       // HW RNE convert
    union { __bf16 b; unsigned short u; } v; v.b = h; return v.u;
}
__device__ __forceinline__ ushort8 cvt8(f32x4 a, f32x4 b) {
    ushort8 o;
#pragma unroll
    for (int i = 0; i < 4; ++i) { o[i] = f2bf(a[i]); o[i + 4] = f2bf(b[i]); }
    return o;
}
__device__ __forceinline__ void gld16(const unsigned short* g, unsigned short* l) {
    __builtin_amdgcn_global_load_lds(
        (const __attribute__((address_space(1))) unsigned int*)g,
        (__attribute__((address_space(3))) unsigned int*)l, 16, 0, 0);
}

#define FENCE() asm volatile("" ::: "memory")
#define BARRIER() do { FENCE(); __builtin_amdgcn_s_barrier(); FENCE(); } while (0)

// ---------------- prep: Weff fold + x conversion ----------------
__global__ __launch_bounds__(256) void prep(
    const float* __restrict__ X, const float* __restrict__ W,
    const float* __restrict__ A, const float* __restrict__ B,
    unsigned short* __restrict__ xbf, unsigned short* __restrict__ Weff)
{
    const int b = blockIdx.x;
    if (b < 512) {
        const int idx = b * 256 + threadIdx.x;
        const int o  = idx >> 7;
        const int kc = (idx & 127) << 3;
        float br[16];
#pragma unroll
        for (int r = 0; r < 16; ++r) br[r] = 2.0f * B[o * 16 + r];
        float acc[8];
        const float* wrow = W + (size_t)o * 1024 + kc;
#pragma unroll
        for (int j = 0; j < 8; ++j) acc[j] = wrow[j];
#pragma unroll
        for (int r = 0; r < 16; ++r) {
            const float* arow = A + r * 1024 + kc;
#pragma unroll
            for (int j = 0; j < 8; ++j) acc[j] += br[r] * arow[j];
        }
        ushort8 o8;
#pragma unroll
        for (int j = 0; j < 8; ++j) o8[j] = f2bf(acc[j]);
        *(ushort8*)(Weff + (size_t)o * 1024 + kc) = o8;
    } else {
        const size_t i = ((size_t)(b - 512) * 256 + threadIdx.x) * 8;
        f32x4 a = *(const f32x4*)(X + i);
        f32x4 c = *(const f32x4*)(X + i + 4);
        *(ushort8*)(xbf + i) = cvt8(a, c);
    }
}

// ---------------- gemm256: 256x128x32, 2 phases/tile, 2 blocks/CU ----------------
// Geometry: BM=256, BN=128, BK=32, 512 thr = 8 waves (2M x 4N). Per-wave out
//   128x32: m-frags rows (2*mt+wr)*16 (mt<4 in A0-half, mt>=4 in A1), n-frags
//   cols (wc+4*nt)*16 (nt=0..1, single B region).
// LDS 48 KiB: 2 bufs x {A0:0, A1:4096, B:8192} ushorts ([128 rows][32] bf16).
// Swizzle (R4-verified, conflicts=0): 16B-chunk c of row r stored at pos
//   c ^ ((r>>1)&3); global source pre-swizzled, LDS dest linear (rule #21).
//   Reader 16-lane phase: chunk_id%8 covers all 8 bank groups exactly 2x -> free.
// Stage slots (tile j): p0 -> A1(j+1) into NEXT buf (last read: tile j-1 p1);
//   p1 -> A0(j+2), B(j+2) into CUR buf (last reads: this tile p0).
// vmcnt: one checkpoint/tile at p1. Outstanding there (5): A0,B(j+1)[j-1 p1],
//   A1(j+1)[j p0], A0,B(j+2)[j p1]. vmcnt(2) retires the oldest 3 = all of
//   tile j+1 (>=2 phases in flight). j==30: vmcnt(0); j>=30: no stage.
#define PHASE_MFMA(LO)                                              \
    do { BARRIER();                                                 \
         asm volatile("s_waitcnt lgkmcnt(0)" ::: "memory");         \
         __builtin_amdgcn_sched_barrier(0); /* rule 18 */           \
         __builtin_amdgcn_s_setprio(1);                             \
         _Pragma("unroll")                                          \
         for (int m2 = 0; m2 < 4; ++m2)                             \
             _Pragma("unroll")                                      \
             for (int n2 = 0; n2 < 2; ++n2)                         \
                 acc[(LO) + m2][n2] = __builtin_amdgcn_mfma_f32_16x16x32_bf16( \
                     fa[(LO) + m2], fb[n2], acc[(LO) + m2][n2], 0, 0, 0);      \
         __builtin_amdgcn_s_setprio(0);                             \
         BARRIER(); } while (0)

__global__ __launch_bounds__(512, 4) void gemm256(
    const unsigned short* __restrict__ Xb,     // bf16 x [M][1024]
    const unsigned short* __restrict__ Wt,     // bf16 Weff [1024][1024]
    const float* __restrict__ bias,            // fp32 [1024]
    float* __restrict__ out)                   // fp32 [M][1024]
{
    extern __shared__ __align__(16) unsigned short lds[];   // 49152 B

    const int t    = threadIdx.x;
    const int lane = t & 63;
    const int w    = t >> 6;
    const int wr   = w >> 2;        // 0..1 (M)
    const int wc   = w & 3;         // 0..3 (N)
    const int r16  = lane & 15;
    const int quad = lane >> 4;

    // XCD-chunked block swizzle (nwg=512 % 8 == 0 -> bijective).
    const int nwg = gridDim.x;
    int swz = blockIdx.x;
    if ((nwg & 7) == 0) swz = (swz & 7) * (nwg >> 3) + (swz >> 3);
    const int bm = (swz >> 3) * 256;           // 64 m-panels
    const int bn = (swz & 7) * 128;            // 8 n-panels share one x panel (L2)

    // ---- staging: thread t owns LDS chunk t of each 8 KiB half-tile ----
    const int r  = t >> 2;                     // half-local row 0..127
    const int sc = (t & 3) ^ ((r >> 1) & 3);   // pre-swizzled src chunk (R4 fix)
    const unsigned short* pA0 = Xb + (size_t)(bm + r) * 1024 + sc * 8;
    const unsigned short* pA1 = pA0 + 131072;  // +128 rows
    const unsigned short* pB  = Wt + (size_t)(bn + r) * 1024 + sc * 8;
    const int lc = t * 8;                      // linear LDS dest (ushorts)

    // ---- reader constants ----
    // fa[mt] = (mt>>2)*4096 + (mt&3)*1024 + aB ; fb[nt] = 8192 + nt*2048 + bB
    const int sw = (quad ^ ((r16 >> 1) & 3)) * 8;   // swizzled chunk offset (R4 fix)
    const int aB = wr * 512 + r16 * 32 + sw;
    const int bB = wc * 512 + r16 * 32 + sw;

    f32x4 acc[8][2];
#pragma unroll
    for (int i = 0; i < 8; ++i)
#pragma unroll
        for (int jj = 0; jj < 2; ++jj)
            acc[i][jj] = (f32x4){0.f, 0.f, 0.f, 0.f};

    // ---- prologue: tile0 (A0,B,A1) -> buf0; tile1 (A0,B) -> buf1 ----
    gld16(pA0,      lds + lc);                 FENCE();
    gld16(pB,       lds + 8192 + lc);          FENCE();
    gld16(pA1,      lds + 4096 + lc);          FENCE();
    gld16(pA0 + 32, lds + 12288 + lc);         FENCE();
    gld16(pB  + 32, lds + 12288 + 8192 + lc);
    asm volatile("s_waitcnt vmcnt(2)" ::: "memory");   // tile0 fully landed
    BARRIER();

#pragma unroll 2
    for (int j = 0; j < 32; ++j) {
        const int cur  = (j & 1) * 12288;
        const int next = cur ^ 12288;
        const unsigned short* Lb = lds + cur;
        const int k1 = (j + 1) * 32, k2 = (j + 2) * 32;

        bf16x8 fa[8], fb[2];

        // ---------- phase 0: reads fa[0..3], fb[0..1]; stage A1(j+1) ----------
#pragma unroll
        for (int mt = 0; mt < 4; ++mt)
            fa[mt] = *(const bf16x8*)(Lb + mt * 1024 + aB);
#pragma unroll
        for (int nt = 0; nt < 2; ++nt)
            fb[nt] = *(const bf16x8*)(Lb + 8192 + nt * 2048 + bB);
        if (j < 31) gld16(pA1 + k1, lds + next + 4096 + lc);
        PHASE_MFMA(0);

        // ---------- phase 1: reads fa[4..7]; stage A0,B(j+2); checkpoint ----------
#pragma unroll
        for (int mt = 4; mt < 8; ++mt)
            fa[mt] = *(const bf16x8*)(Lb + 4096 + (mt - 4) * 1024 + aB);
        if (j < 30) { gld16(pA0 + k2, lds + cur + lc);              FENCE();
                      gld16(pB  + k2, lds + cur + 8192 + lc); }
        if (j < 30)       asm volatile("s_waitcnt vmcnt(2)" ::: "memory");
        else if (j == 30) asm volatile("s_waitcnt vmcnt(0)" ::: "memory");
        PHASE_MFMA(4);
    }

    // ---- epilogue: frag (mt,nt) -> rows bm+(2mt+wr)*16+quad*4, cols bn+(wc+4nt)*16+r16 ----
    const int orow0 = bm + wr * 16 + quad * 4;
    const int ocol0 = bn + wc * 16 + r16;
#pragma unroll
    for (int nt = 0; nt < 2; ++nt) {
        const float bv = bias[ocol0 + nt * 64];
#pragma unroll
        for (int mt = 0; mt < 8; ++mt) {
            float* orow = out + (size_t)(orow0 + mt * 32) * 1024 + (ocol0 + nt * 64);
#pragma unroll
            for (int i = 0; i < 4; ++i)
                orow[(size_t)i * 1024] = acc[mt][nt][i] + bv;
        }
    }
}

// ---------------- fallback gemm (ws too small): old 128x128, fp32 A ----------------
template <bool XF32>
__global__ __launch_bounds__(256) void gemm_bt(
    const void* __restrict__ X_, const unsigned short* __restrict__ Wt,
    const float* __restrict__ bias, float* __restrict__ out)
{
    __shared__ __align__(16) unsigned short lA[128 * 32];
    __shared__ __align__(16) unsigned short lB[128 * 32];

    const int t    = threadIdx.x;
    const int lane = t & 63;
    const int w    = t >> 6;
    const int bm   = blockIdx.x * 128;
    const int bn   = blockIdx.y * 128;
    const int wm   = (w & 1) * 64;
    const int wn   = (w >> 1) * 64;
    const int r16  = lane & 15;
    const int quad = lane >> 4;

    const int srow = t >> 2;
    const int gc   = (t & 3) ^ ((srow >> 1) & 3);
    unsigned short* lsA = lA + t * 8;
    unsigned short* lsB = lB + t * 8;
    const size_t ga0 = (size_t)(bm + srow) * 1024 + gc * 8;
    const size_t ga1 = (size_t)(bm + srow + 64) * 1024 + gc * 8;
    const unsigned short* gB0 = Wt + (size_t)(bn + srow) * 1024 + gc * 8;

    const int p    = (quad ^ ((r16 >> 1) & 3)) * 8;
    const int aoff = (wm + r16) * 32 + p;
    const int boff = (wn + r16) * 32 + p;

    const unsigned short* Xb = (const unsigned short*)X_;
    const float*          Xf = (const float*)X_;

    f32x4 acc[4][4];
#pragma unroll
    for (int i = 0; i < 4; ++i)
#pragma unroll
        for (int j = 0; j < 4; ++j) {
            f32x4 z = {0.f, 0.f, 0.f, 0.f};
            acc[i][j] = z;
        }

    for (int kt = 0; kt < 1024; kt += 32) {
        if (XF32) {
            f32x4 a0 = *(const f32x4*)(Xf + ga0 + kt);
            f32x4 a1 = *(const f32x4*)(Xf + ga0 + kt + 4);
            f32x4 a2 = *(const f32x4*)(Xf + ga1 + kt);
            f32x4 a3 = *(const f32x4*)(Xf + ga1 + kt + 4);
            *(ushort8*)lsA          = cvt8(a0, a1);
            *(ushort8*)(lsA + 2048) = cvt8(a2, a3);
        } else {
            gld16(Xb + ga0 + kt, lsA);
            gld16(Xb + ga1 + kt, lsA + 2048);
        }
        gld16(gB0 + kt,             lsB);
        gld16(gB0 + kt + 64 * 1024, lsB + 2048);
        __syncthreads();

        bf16x8 fa[4], fb[4];
#pragma unroll
        for (int mt = 0; mt < 4; ++mt) fa[mt] = *(const bf16x8*)(lA + aoff + mt * 16 * 32);
#pragma unroll
        for (int nt = 0; nt < 4; ++nt) fb[nt] = *(const bf16x8*)(lB + boff + nt * 16 * 32);

#pragma unroll
        for (int mt = 0; mt < 4; ++mt)
#pragma unroll
            for (int nt = 0; nt < 4; ++nt)
                acc[mt][nt] = __builtin_amdgcn_mfma_f32_16x16x32_bf16(
                    fa[mt], fb[nt], acc[mt][nt], 0, 0, 0);

        __syncthreads();
    }

    const int orow0 = bm + wm + quad * 4;
    const int ocol0 = bn + wn + r16;
#pragma unroll
    for (int nt = 0; nt < 4; ++nt) {
        const float bv = bias[ocol0 + nt * 16];
#pragma unroll
        for (int mt = 0; mt < 4; ++mt)
#pragma unroll
            for (int i = 0; i < 4; ++i)
                out[(size_t)(orow0 + mt * 16 + i) * 1024 + (ocol0 + nt * 16)] =
                    acc[mt][nt][i] + bv;
    }
}

extern "C" void kernel_launch(void* const* d_in, const int* in_sizes, int n_in,
                              void* d_out, int out_size, void* d_ws, size_t ws_size,
                              hipStream_t stream) {
    const float* x  = (const float*)d_in[0];   // [M][1024]
    const float* W  = (const float*)d_in[1];   // [1024][1024]
    const float* b  = (const float*)d_in[2];   // [1024]
    const float* A  = (const float*)d_in[3];   // [16][1024]
    const float* Bm = (const float*)d_in[4];   // [1024][16]
    float* out = (float*)d_out;

    const int M = in_sizes[0] / 1024;          // 16384

    const bool fast = (ws_size >= ((size_t)(M)*1024*2 + (2u << 20) + 4096)) &&
                      (M % 256 == 0);
    if (fast) {
        unsigned short* xbf  = (unsigned short*)d_ws;
        unsigned short* Weff = xbf + (size_t)M * 1024;
        hipLaunchKernelGGL(prep, dim3(512 + M / 2), dim3(256), 0, stream,
                           x, W, A, Bm, xbf, Weff);
        hipLaunchKernelGGL(gemm256, dim3((M / 256) * 8), dim3(512), 49152, stream,
                           xbf, Weff, b, out);
    } else {
        unsigned short* Weff = (unsigned short*)d_ws;
        hipLaunchKernelGGL(prep, dim3(512), dim3(256), 0, stream,
                           x, W, A, Bm, (unsigned short*)nullptr, Weff);
        hipLaunchKernelGGL((gemm_bt<true>), dim3(M / 128, 8), dim3(256), 0, stream,
                           (const void*)x, Weff, b, out);
    }
}